// Round 10
// baseline (119.008 us; speedup 1.0000x reference)
//
#include <hip/hip_runtime.h>
#include <hip/hip_bf16.h>
#include <math.h>

#define BB 2048   // batch per view
#define NN 4096   // 2*BB
#define DD 128    // feature dim per modality
#define CC 512    // classes
#define NSIM 528  // 32*33/2 upper-triangle 128x128 tiles
#define NPROTO 128// (4096/64 row-groups) x 2 class-halves

typedef __attribute__((ext_vector_type(8))) short bf16x8;   // 8 bf16 = 4 VGPRs
typedef __attribute__((ext_vector_type(4))) float f32x4;

#define LDS_PTR(p) ((__attribute__((address_space(3))) uint32_t*)(p))
#define GLB_PTR(p) ((const __attribute__((address_space(1))) uint32_t*)(p))

// ---------------- K1: fused l2-normalize(feats) + scale(centroids) + rowsum zero -------
// 512-thr blocks, 1 row per wave, loops all 3 modalities. grid = NN/8 + CC/8 = 576.
__global__ __launch_bounds__(512) void k_normprep(
    const float* __restrict__ si, const float* __restrict__ sj,
    const float* __restrict__ ci, const float* __restrict__ cj,
    const float* __restrict__ pi, const float* __restrict__ pj,
    const float* __restrict__ cst, const float* __restrict__ cca,
    const float* __restrict__ cpl, const float* __restrict__ conc,
    __hip_bfloat16* __restrict__ fbf, __hip_bfloat16* __restrict__ cbf,
    float* __restrict__ rowsum) {
  const int tid = threadIdx.x;
  const int w   = tid >> 6;
  const int t   = tid & 63;

  // fold the rowsum zeroing into this dispatch (replaces a memset node)
  if (blockIdx.x < 2) {
    const int i = (blockIdx.x * 512 + tid) * 4;
    *(float4*)(rowsum + i) = make_float4(0.f, 0.f, 0.f, 0.f);
  }

  if (blockIdx.x < NN / 8) {
    const int row = blockIdx.x * 8 + w;
    const int r = (row < BB) ? row : row - BB;
    #pragma unroll
    for (int m = 0; m < 3; ++m) {
      const float* src;
      if (m == 0)      src = (row < BB) ? si : sj;
      else if (m == 1) src = (row < BB) ? ci : cj;
      else             src = (row < BB) ? pi : pj;
      const float sqw = (m == 0) ? 0.632455532033676f : 0.547722557505166f;  // sqrt(w_m)
      float2 v = ((const float2*)(src + (size_t)r * DD))[t];
      float ss = v.x * v.x + v.y * v.y;
      #pragma unroll
      for (int k = 32; k >= 1; k >>= 1) ss += __shfl_xor(ss, k);
      const float inv = sqw / fmaxf(sqrtf(ss), 1e-12f);
      __hip_bfloat16* db = fbf + (size_t)m * NN * DD + (size_t)row * DD;
      db[2 * t]     = __float2bfloat16(v.x * inv);
      db[2 * t + 1] = __float2bfloat16(v.y * inv);
    }
  } else {
    const int crow = (blockIdx.x - NN / 8) * 8 + w;   // 0..511
    #pragma unroll
    for (int m = 0; m < 3; ++m) {
      const float* src = (m == 0) ? cst : (m == 1) ? cca : cpl;
      const float sqw = (m == 0) ? 0.632455532033676f : 0.547722557505166f;
      const float sc = sqw / (conc[m * CC + crow] + 1e-12f);
      float2 v = ((const float2*)(src + (size_t)crow * DD))[t];
      __hip_bfloat16* db = cbf + (size_t)m * CC * DD + (size_t)crow * DD;
      db[2 * t]     = __float2bfloat16(v.x * sc);
      db[2 * t + 1] = __float2bfloat16(v.y * sc);
    }
  }
}

// ---------------- K2: merged sim-Gram + proto-logits kernel ----------------
// blocks [0, 528): symmetric K=384 Gram tile (128x128), global_load_lds staging
//   (m97 structure: DMA -> barrier -> compute -> barrier; pre-swizzled global source)
// blocks [528, 656): proto partial — 64 rows x 256 classes, partial lse
__global__ __launch_bounds__(256, 3) void k_main(const __hip_bfloat16* __restrict__ fbf,
                                                 const __hip_bfloat16* __restrict__ cbf,
                                                 const int* __restrict__ labels,
                                                 float* __restrict__ rowsum,
                                                 float* __restrict__ pos_e,
                                                 float* __restrict__ diag_e,
                                                 float* __restrict__ pmax_g,
                                                 float* __restrict__ psum_g,
                                                 float* __restrict__ zl_g) {
  __shared__ bf16x8 As[1024];   // 16 KB: [row 0..127][slot 0..7], slot holds chunk slot^(row&7)
  __shared__ bf16x8 Bs[1024];   // 16 KB

  const int tid  = threadIdx.x;
  const int lane = tid & 63;
  const int wid  = tid >> 6;
  const int l15  = lane & 15;
  const int kg   = lane >> 4;

  if (blockIdx.x < NSIM) {
    // ================= SIM path =================
    int tB = blockIdx.x;
    int by = 0;
    while (tB >= 32 - by) { tB -= 32 - by; ++by; }
    const int bx = by + tB;
    const bool diag = (by == bx);
    const int rowBase = by * 128;
    const int colBase = bx * 128;

    const int wr = wid >> 1, wc = wid & 1;
    // staging map (inverse-swizzled global source; LDS written linearly by DMA):
    // instr q covers LDS slots [q*256 + wid*64, +64); lane's slot s = q*256+wid*64+lane
    // row = s>>3 = q*32 + wid*8 + (lane>>3); sl = lane&7; chunk kc = sl ^ (row&7)
    const int rl = lane >> 3;            // 0..7 == row&7 for every q
    const int kc = (lane & 7) ^ rl;      // global 16B-chunk index for this lane

    f32x4 acc[4][4] = {};

    for (int t = 0; t < 6; ++t) {        // K = 384 = 6 x BK64
      const __hip_bfloat16* F = fbf + (size_t)(t >> 1) * NN * DD + (t & 1) * 64;
      #pragma unroll
      for (int q = 0; q < 4; ++q) {
        const int row = q * 32 + wid * 8 + rl;
        __builtin_amdgcn_global_load_lds(
            GLB_PTR(F + (size_t)(rowBase + row) * DD + kc * 8),
            LDS_PTR(&As[q * 256 + wid * 64]), 16, 0, 0);
        if (!diag)
          __builtin_amdgcn_global_load_lds(
              GLB_PTR(F + (size_t)(colBase + row) * DD + kc * 8),
              LDS_PTR(&Bs[q * 256 + wid * 64]), 16, 0, 0);
      }
      __syncthreads();                   // compiler drains vmcnt before s_barrier

      const bf16x8* Bsrc = diag ? As : Bs;
      #pragma unroll
      for (int ks2 = 0; ks2 < 2; ++ks2) {
        bf16x8 a[4], b[4];
        const int ch = (ks2 * 4 + kg) ^ (l15 & 7);   // same involution as the store side
        #pragma unroll
        for (int ti = 0; ti < 4; ++ti)
          a[ti] = As[(wr * 64 + ti * 16 + l15) * 8 + ch];
        #pragma unroll
        for (int tj = 0; tj < 4; ++tj)
          b[tj] = Bsrc[(wc * 64 + tj * 16 + l15) * 8 + ch];
        #pragma unroll
        for (int ti = 0; ti < 4; ++ti)
          #pragma unroll
          for (int tj = 0; tj < 4; ++tj)
            acc[ti][tj] = __builtin_amdgcn_mfma_f32_16x16x32_bf16(a[ti], b[tj], acc[ti][tj], 0, 0, 0);
      }
      if (t < 5) __syncthreads();        // all waves done reading before next DMA overwrite
    }

    float csum[4] = {0.f, 0.f, 0.f, 0.f};
    #pragma unroll
    for (int ti = 0; ti < 4; ++ti) {
      #pragma unroll
      for (int j = 0; j < 4; ++j) {
        const int i = rowBase + wr * 64 + ti * 16 + kg * 4 + j;
        float rsum = 0.f;
        #pragma unroll
        for (int tj = 0; tj < 4; ++tj) {
          const int jcol = colBase + wc * 64 + tj * 16 + l15;
          const float e = __expf(2.0f * acc[ti][tj][j]);
          rsum += e;
          csum[tj] += e;
          if (diag) {
            if (jcol == i) diag_e[i] = e;
          } else if (jcol == ((i + BB) & (NN - 1))) {
            pos_e[i] = e;
            pos_e[jcol] = e;
          }
        }
        #pragma unroll
        for (int msk = 8; msk >= 1; msk >>= 1) rsum += __shfl_xor(rsum, msk);
        if (l15 == 0) atomicAdd(&rowsum[i], rsum);
      }
    }
    if (!diag) {
      #pragma unroll
      for (int tj = 0; tj < 4; ++tj) {
        float v = csum[tj];
        v += __shfl_xor(v, 16);
        v += __shfl_xor(v, 32);
        if (lane < 16) atomicAdd(&rowsum[colBase + wc * 64 + tj * 16 + l15], v);
      }
    }
  } else {
    // ========== PROTO path: 64 rows x 256 classes, 16 MFMA : 8 loads per K-step =======
    float* wmaxs = (float*)As;            // [4][64]
    float* wsums = wmaxs + 256;           // [4][64]
    int*   slab  = (int*)(wsums + 256);   // [64]

    const int bidp = blockIdx.x - NSIM;   // 0..127
    const int half = bidp & 1;
    const int row0 = (bidp >> 1) * 64;
    const int cbase = half * 256 + wid * 64;

    if (tid < 64) slab[tid] = labels[row0 + tid];
    __syncthreads();

    f32x4 acc[4][4] = {};                 // [row-frag][col-frag]
    #pragma unroll
    for (int ks = 0; ks < 12; ++ks) {
      const int koff = (ks & 3) * 32 + kg * 8;
      const __hip_bfloat16* F  = fbf + (size_t)(ks >> 2) * NN * DD + koff;
      const __hip_bfloat16* Cm = cbf + (size_t)(ks >> 2) * CC * DD + koff;
      bf16x8 af[4], bfr[4];
      #pragma unroll
      for (int ti = 0; ti < 4; ++ti)
        af[ti] = *(const bf16x8*)(F + (size_t)(row0 + ti * 16 + l15) * DD);
      #pragma unroll
      for (int tj = 0; tj < 4; ++tj)
        bfr[tj] = *(const bf16x8*)(Cm + (size_t)(cbase + tj * 16 + l15) * DD);
      #pragma unroll
      for (int ti = 0; ti < 4; ++ti)
        #pragma unroll
        for (int tj = 0; tj < 4; ++tj)
          acc[ti][tj] = __builtin_amdgcn_mfma_f32_16x16x32_bf16(af[ti], bfr[tj], acc[ti][tj], 0, 0, 0);
    }

    // label logit capture (exactly one lane device-wide matches each row)
    #pragma unroll
    for (int ti = 0; ti < 4; ++ti) {
      #pragma unroll
      for (int j = 0; j < 4; ++j) {
        const int r = ti * 16 + kg * 4 + j;
        #pragma unroll
        for (int tj = 0; tj < 4; ++tj) {
          const int c = cbase + tj * 16 + l15;
          if (c == slab[r]) zl_g[row0 + r] = acc[ti][tj][j];
        }
      }
    }

    // per-wave per-row max over its 64-class slice
    #pragma unroll
    for (int ti = 0; ti < 4; ++ti) {
      #pragma unroll
      for (int j = 0; j < 4; ++j) {
        const int r = ti * 16 + kg * 4 + j;
        float mx = acc[ti][0][j];
        #pragma unroll
        for (int tj = 1; tj < 4; ++tj) mx = fmaxf(mx, acc[ti][tj][j]);
        #pragma unroll
        for (int msk = 8; msk >= 1; msk >>= 1) mx = fmaxf(mx, __shfl_xor(mx, msk));
        if (l15 == 0) wmaxs[wid * 64 + r] = mx;
      }
    }
    __syncthreads();

    #pragma unroll
    for (int ti = 0; ti < 4; ++ti) {
      #pragma unroll
      for (int j = 0; j < 4; ++j) {
        const int r = ti * 16 + kg * 4 + j;
        const float bmx = fmaxf(fmaxf(wmaxs[0 * 64 + r], wmaxs[1 * 64 + r]),
                                fmaxf(wmaxs[2 * 64 + r], wmaxs[3 * 64 + r]));
        float se = 0.f;
        #pragma unroll
        for (int tj = 0; tj < 4; ++tj) se += __expf(acc[ti][tj][j] - bmx);
        #pragma unroll
        for (int msk = 8; msk >= 1; msk >>= 1) se += __shfl_xor(se, msk);
        if (l15 == 0) wsums[wid * 64 + r] = se;
      }
    }
    __syncthreads();

    if (tid < 64) {
      const int r = tid;
      const float bmx = fmaxf(fmaxf(wmaxs[0 * 64 + r], wmaxs[1 * 64 + r]),
                              fmaxf(wmaxs[2 * 64 + r], wmaxs[3 * 64 + r]));
      const float s = wsums[0 * 64 + r] + wsums[1 * 64 + r] +
                      wsums[2 * 64 + r] + wsums[3 * 64 + r];
      pmax_g[(size_t)half * NN + row0 + r] = bmx;
      psum_g[(size_t)half * NN + row0 + r] = s;
    }
  }
}

// ---------------- K4: final scalar reduce (combines proto halves exactly) -------------
__global__ void k_final(const float* __restrict__ rowsum, const float* __restrict__ pos_e,
                        const float* __restrict__ diag_e, const float* __restrict__ pmax_g,
                        const float* __restrict__ psum_g, const float* __restrict__ zl_g,
                        float* __restrict__ out) {
  __shared__ float redA[4], redB[4];
  const int tid = threadIdx.x;
  float sa = 0.f, sb = 0.f;
  for (int i = tid; i < NN; i += 256) {
    sa += __logf(rowsum[i] - diag_e[i]) - __logf(pos_e[i]);
    const float m0 = pmax_g[i], m1 = pmax_g[NN + i];
    const float M = fmaxf(m0, m1);
    const float s = psum_g[i] * __expf(m0 - M) + psum_g[NN + i] * __expf(m1 - M);
    sb += M + __logf(s) - zl_g[i];
  }
  const int lane = tid & 63, wv = tid >> 6;
  #pragma unroll
  for (int k = 32; k >= 1; k >>= 1) { sa += __shfl_xor(sa, k); sb += __shfl_xor(sb, k); }
  if (lane == 0) { redA[wv] = sa; redB[wv] = sb; }
  __syncthreads();
  if (tid == 0) {
    const float la = redA[0] + redA[1] + redA[2] + redA[3];
    const float lb = redB[0] + redB[1] + redB[2] + redB[3];
    out[0] = la / (float)NN + lb / (float)NN;
  }
}

extern "C" void kernel_launch(void* const* d_in, const int* in_sizes, int n_in,
                              void* d_out, int out_size, void* d_ws, size_t ws_size,
                              hipStream_t stream) {
  (void)in_sizes; (void)n_in; (void)out_size; (void)ws_size;
  const float* si  = (const float*)d_in[0];
  const float* sj  = (const float*)d_in[1];
  const float* ci  = (const float*)d_in[2];
  const float* cj  = (const float*)d_in[3];
  const float* pi  = (const float*)d_in[4];
  const float* pj  = (const float*)d_in[5];
  const int*   lab = (const int*)d_in[6];
  const float* cst = (const float*)d_in[7];
  const float* cca = (const float*)d_in[8];
  const float* cpl = (const float*)d_in[9];
  const float* cnc = (const float*)d_in[10];

  // ws layout (~3.6 MB): small f32 arrays + bf16 feats/centroids
  float* ws     = (float*)d_ws;
  float* rowsum = ws;                          // 4096
  float* pos_e  = rowsum + NN;                 // 4096
  float* diag_e = pos_e + NN;                  // 4096
  float* pmax_g = diag_e + NN;                 // 2*4096
  float* psum_g = pmax_g + 2 * NN;             // 2*4096
  float* zl_g   = psum_g + 2 * NN;             // 4096
  __hip_bfloat16* fbf = (__hip_bfloat16*)(zl_g + NN);           // 3*4096*128 bf16 = 3 MB
  __hip_bfloat16* cbf = fbf + (size_t)3 * NN * DD;              // 3*512*128 bf16 = 384 KB

  k_normprep<<<NN / 8 + CC / 8, 512, 0, stream>>>(si, sj, ci, cj, pi, pj,
                                                  cst, cca, cpl, cnc, fbf, cbf, rowsum);
  k_main<<<NSIM + NPROTO, 256, 0, stream>>>(fbf, cbf, lab, rowsum, pos_e, diag_e,
                                            pmax_g, psum_g, zl_g);
  k_final<<<1, 256, 0, stream>>>(rowsum, pos_e, diag_e, pmax_g, psum_g, zl_g, (float*)d_out);
}